// Round 7
// baseline (381.283 us; speedup 1.0000x reference)
//
#include <hip/hip_runtime.h>
#include <hip/hip_bf16.h>

// ---------------------------------------------------------------------------
// SpatialInteraction: per-batch channel self-attention
//   S = X X^T  (c=1024, n=4096), attn = softmax_rows(S), out = attn X
// Pipeline: cvt+transpose -> SYMMETRIC triangle bt-GEMM (S) -> softmax ->
//           256^2 bt-GEMM (out).
// R7: GEMM loop = R5's proven checkpoint pipeline (passed post-timing;
// R6's fine-phase variant raced and is abandoned). New: GEMM1 exploits
// S symmetry — compute only the 10 lower-triangle 256x256 tile pairs per
// batch (of 16) and write both C[i,j] and C[j,i]^T from the same acc via
// the LDS-transpose epilogue. 37.5% of GEMM1 work eliminated.
// ---------------------------------------------------------------------------

typedef float  f32x4  __attribute__((ext_vector_type(4)));
typedef __bf16 bf16x8 __attribute__((ext_vector_type(8)));

#define BATCH 16
#define C_DIM 1024
#define N_DIM 4096

#define WAITVM(N) asm volatile("s_waitcnt vmcnt(" #N ")" ::: "memory")

__device__ __forceinline__ void bar_() {
  asm volatile("" ::: "memory");
  __builtin_amdgcn_s_barrier();
  asm volatile("" ::: "memory");
}

__device__ __forceinline__ unsigned short f2bf(float f) {
  unsigned u = __float_as_uint(f);
  u += 0x7fffu + ((u >> 16) & 1u);        // round-to-nearest-even
  return (unsigned short)(u >> 16);
}

__device__ __forceinline__ void gld_lds16(const void* g, void* l) {
  __builtin_amdgcn_global_load_lds(
      (const __attribute__((address_space(1))) unsigned int*)g,
      (__attribute__((address_space(3))) unsigned int*)l, 16, 0, 0);
}

// ---------------------------------------------------------------------------
// Kernel 0: fp32 -> bf16 copy (xb[c][n]) + transposed copy (xbT[n][c]).
// ---------------------------------------------------------------------------
__global__ __launch_bounds__(256) void cvt_xpose(const float* __restrict__ x,
                                                 unsigned short* __restrict__ xb,
                                                 unsigned short* __restrict__ xbT) {
  __shared__ unsigned short tile[64][68];
  const int b  = blockIdx.z;
  const int c0 = blockIdx.y * 64;
  const int n0 = blockIdx.x * 64;
  const int t  = threadIdx.x;

  const float* xp = x + ((size_t)b * C_DIM + c0) * N_DIM + n0;
  const int tn = (t & 15) * 4;
  const int tc = t >> 4;

#pragma unroll
  for (int i = 0; i < 4; ++i) {
    const int c = i * 16 + tc;
    const float4 v = *(const float4*)(xp + (size_t)c * N_DIM + tn);
    ushort4 u;
    u.x = f2bf(v.x); u.y = f2bf(v.y); u.z = f2bf(v.z); u.w = f2bf(v.w);
    *(ushort4*)&tile[c][tn] = u;
    *(ushort4*)(xb + ((size_t)b * C_DIM + c0 + c) * N_DIM + n0 + tn) = u;
  }
  __syncthreads();

  const int pc = (t & 15) * 4;
  const int pn = t >> 4;
#pragma unroll
  for (int i = 0; i < 4; ++i) {
    const int n = i * 16 + pn;
    ushort4 u;
    u.x = tile[pc + 0][n];
    u.y = tile[pc + 1][n];
    u.z = tile[pc + 2][n];
    u.w = tile[pc + 3][n];
    *(ushort4*)(xbT + ((size_t)b * N_DIM + n0 + n) * C_DIM + c0 + pc) = u;
  }
}

// ---------------------------------------------------------------------------
// 256^2 bt-GEMM helpers. LDS layout per matrix per buffer: 256 rows x 64
// bf16 (8 x 16B chunks/row); swizzle chunk' = chunk ^ (row & 7), applied to
// the GLOBAL source on stage and to the ds_read address (LDS stays linear).
// ---------------------------------------------------------------------------

template<int H>
__device__ __forceinline__ void stage_half(const unsigned short* __restrict__ Gb,
                                           int ld, int k0,
                                           unsigned short* matbase, int tid) {
  unsigned short* lhalf = matbase + H * 128 * 64;
#pragma unroll
  for (int i = 0; i < 2; ++i) {
    const int chunk = i * 512 + tid;     // 0..1023 within half
    const int row   = chunk >> 3;        // 0..127
    const int c16   = chunk & 7;
    const int grow  = H * 128 + row;
    gld_lds16(Gb + (size_t)grow * ld + k0 + ((c16 ^ (row & 7)) * 8),
              lhalf + chunk * 8);
  }
}

template<int MH>
__device__ __forceinline__ void loadA(const unsigned short* __restrict__ As,
                                      bf16x8 (&a)[4][2], int wrow, int r, int kg) {
#pragma unroll
  for (int i = 0; i < 4; ++i) {
    const int row = MH * 128 + wrow * 64 + i * 16 + r;
#pragma unroll
    for (int kk = 0; kk < 2; ++kk) {
      const int c = kk * 4 + kg;
      a[i][kk] = *(const bf16x8*)(As + row * 64 + ((c ^ (row & 7)) * 8));
    }
  }
}

template<int NH>
__device__ __forceinline__ void loadB(const unsigned short* __restrict__ Bs,
                                      bf16x8 (&b)[2][2], int wcol, int r, int kg) {
#pragma unroll
  for (int j = 0; j < 2; ++j) {
    const int row = NH * 128 + wcol * 32 + j * 16 + r;
#pragma unroll
    for (int kk = 0; kk < 2; ++kk) {
      const int c = kk * 4 + kg;
      b[j][kk] = *(const bf16x8*)(Bs + row * 64 + ((c ^ (row & 7)) * 8));
    }
  }
}

template<int MH, int NH>
__device__ __forceinline__ void mfma16(const bf16x8 (&a)[4][2],
                                       const bf16x8 (&b)[2][2],
                                       f32x4 (&acc)[8][4]) {
  __builtin_amdgcn_s_setprio(1);
#pragma unroll
  for (int i = 0; i < 4; ++i)
#pragma unroll
    for (int j = 0; j < 2; ++j)
#pragma unroll
      for (int kk = 0; kk < 2; ++kk)
        acc[MH * 4 + i][NH * 2 + j] = __builtin_amdgcn_mfma_f32_16x16x32_bf16(
            a[i][kk], b[j][kk], acc[MH * 4 + i][NH * 2 + j], 0, 0, 0);
  __builtin_amdgcn_s_setprio(0);
}

// R5-proven checkpoint main loop over K (2 counted-vmcnt waits + 2 barriers
// per K-tile). Fills acc from panels Ab (rows) x Bb (rows, B^T sense).
__device__ __forceinline__ void gemm_loop(const unsigned short* __restrict__ Ab,
                                          const unsigned short* __restrict__ Bb,
                                          int lda, int ldb, int K,
                                          unsigned short* lds, int tid,
                                          int wrow, int wcol, int r, int kg,
                                          f32x4 (&acc)[8][4]) {
  bf16x8 a[4][2], b0[2][2], b1[2][2];
  const int NT = K / 64;

  // prologue: stage tile 0 in checkpoint-group order A0,B0,B1,A1
  {
    unsigned short* A0 = lds;          // buf 0
    unsigned short* B0 = lds + 16384;
    stage_half<0>(Ab, lda, 0, A0, tid);
    stage_half<0>(Bb, ldb, 0, B0, tid);
    stage_half<1>(Bb, ldb, 0, B0, tid);
    stage_half<1>(Ab, lda, 0, A0, tid);
  }
  WAITVM(2); bar_();   // A0,B0,B1 of tile 0 landed (A1 still in flight)

  for (int t = 0; t < NT - 1; ++t) {
    const unsigned short* Ac = lds + (t & 1) * 32768;
    const unsigned short* Bc = Ac + 16384;
    unsigned short* An = lds + ((t + 1) & 1) * 32768;
    unsigned short* Bn = An + 16384;
    const int k1 = (t + 1) * 64;

    // seg1: stage {A0',B0',B1'}; compute quads (0,0),(0,1)
    stage_half<0>(Ab, lda, k1, An, tid);
    stage_half<0>(Bb, ldb, k1, Bn, tid);
    stage_half<1>(Bb, ldb, k1, Bn, tid);
    loadA<0>(Ac, a, wrow, r, kg);
    loadB<0>(Bc, b0, wcol, r, kg);
    mfma16<0, 0>(a, b0, acc);
    loadB<1>(Bc, b1, wcol, r, kg);
    mfma16<0, 1>(a, b1, acc);
    // CP_mid: queue [A1(t), A0',B0',B1'] = 8 -> drain A1(t)
    WAITVM(6); bar_();

    // seg2: stage {A1'}; compute quads (1,0),(1,1)
    stage_half<1>(Ab, lda, k1, An, tid);
    loadA<1>(Ac, a, wrow, r, kg);
    mfma16<1, 0>(a, b0, acc);
    mfma16<1, 1>(a, b1, acc);
    // CP_end: queue [A0',B0',B1', A1'] = 8 -> drain A0',B0',B1'
    WAITVM(2); bar_();
  }

  // peeled last tile
  {
    const unsigned short* Ac = lds + ((NT - 1) & 1) * 32768;
    const unsigned short* Bc = Ac + 16384;
    loadA<0>(Ac, a, wrow, r, kg);
    loadB<0>(Bc, b0, wcol, r, kg);
    mfma16<0, 0>(a, b0, acc);
    loadB<1>(Bc, b1, wcol, r, kg);
    mfma16<0, 1>(a, b1, acc);
    WAITVM(0); bar_();               // A1 of last tile landed
    loadA<1>(Ac, a, wrow, r, kg);
    mfma16<1, 0>(a, b0, acc);
    mfma16<1, 1>(a, b1, acc);
  }
}

// ---------------------------------------------------------------------------
// Kernel 1: symmetric GEMM  S = Xb Xb^T per batch, triangle tiles only.
// grid = 10 * BATCH blocks (1D). Off-diagonal blocks write C[i,j] and
// C[j,i]^T from the same accumulators.
// ---------------------------------------------------------------------------
__global__ __launch_bounds__(512, 2)
void gemm_sym(const unsigned short* __restrict__ A,
              float* __restrict__ C,
              int K, int lda, int ldc, long sA, long sC) {
  __shared__ __align__(16) unsigned char smem[131072];
  unsigned short* lds = (unsigned short*)smem;

  // XCD swizzle (nwg = 160, %8 == 0), then triangle decode.
  const int nwg  = gridDim.x;
  const int orig = blockIdx.x;
  const int wg   = (orig & 7) * (nwg >> 3) + (orig >> 3);
  const int bz   = wg / 10;
  const int p    = wg % 10;
  int ti = 0;
  while ((ti + 1) * (ti + 2) / 2 <= p) ++ti;     // ti in 0..3
  const int tj = p - ti * (ti + 1) / 2;          // tj in 0..ti

  const int tid  = threadIdx.x;
  const int lane = tid & 63;
  const int wid  = tid >> 6;
  const int wrow = wid >> 2;
  const int wcol = wid & 3;
  const int r    = lane & 15;
  const int kg   = lane >> 4;

  const unsigned short* Ab = A + (size_t)bz * sA + (size_t)ti * 256 * lda;
  const unsigned short* Bb = A + (size_t)bz * sA + (size_t)tj * 256 * lda;

  f32x4 acc[8][4] = {};
  gemm_loop(Ab, Bb, lda, lda, K, lds, tid, wrow, wcol, r, kg, acc);

  // epilogue: LDS transpose staging; write C[i,j]; if i!=j also C[j,i]^T.
  float* Cb = C + (size_t)bz * sC;
  const int rb = ti * 256;
  const int cb = tj * 256;
  float* lf = (float*)smem;          // 64 x 260 f32 scratch
  __syncthreads();
#pragma unroll
  for (int q = 0; q < 4; ++q) {
    if (wrow == (q & 1)) {
      const int MH = q >> 1;
#pragma unroll
      for (int i = 0; i < 4; ++i) {
#pragma unroll
        for (int n = 0; n < 4; ++n) {
          const int col  = (n >> 1) * 128 + wcol * 32 + (n & 1) * 16 + r;
          const int lrow = i * 16 + kg * 4;
          const f32x4 v = acc[MH * 4 + i][n];
#pragma unroll
          for (int j = 0; j < 4; ++j)
            lf[(lrow + j) * 260 + col] = v[j];
        }
      }
    }
    __syncthreads();
    // normal store: rows rb+q*64.., cols cb..cb+255
#pragma unroll
    for (int i = 0; i < 8; ++i) {
      const int chunk = i * 512 + tid;     // 0..4095
      const int row   = chunk >> 6;        // 0..63
      const int cp    = (chunk & 63) * 4;  // 0..252
      const f32x4 v = *(const f32x4*)&lf[row * 260 + cp];
      *(f32x4*)&Cb[(size_t)(rb + q * 64 + row) * ldc + cb + cp] = v;
    }
    if (ti != tj) {
      // transposed store: rows cb..cb+255, cols rb+q*64 .. +63
#pragma unroll
      for (int i = 0; i < 8; ++i) {
        const int chunk = i * 512 + tid;     // 0..4095
        const int orow  = chunk >> 4;        // 0..255 (col of lf)
        const int ocp   = (chunk & 15) * 4;  // 0..60  (row of lf)
        f32x4 v;
#pragma unroll
        for (int j = 0; j < 4; ++j)
          v[j] = lf[(ocp + j) * 260 + orow];
        *(f32x4*)&Cb[(size_t)(cb + orow) * ldc + rb + q * 64 + ocp] = v;
      }
    }
    __syncthreads();
  }
}

// ---------------------------------------------------------------------------
// Kernel 3: C[M][N] = A[M][K] * B[N][K]^T (R5 unchanged).
// 1D grid = gx * 4 * BATCH blocks, 512 threads. M fixed at 1024 (4 tiles).
// ---------------------------------------------------------------------------
__global__ __launch_bounds__(512, 2)
void gemm_bt256(const unsigned short* __restrict__ A,
                const unsigned short* __restrict__ B,
                float* __restrict__ C,
                int K, int lda, int ldb, int ldc,
                long sA, long sB, long sC, int gx) {
  __shared__ __align__(16) unsigned char smem[131072];
  unsigned short* lds = (unsigned short*)smem;

  const int nwg  = gridDim.x;
  const int orig = blockIdx.x;
  const int wg   = (orig & 7) * (nwg >> 3) + (orig >> 3);
  const int by   = wg & 3;
  const int bx   = (wg >> 2) % gx;
  const int bz   = wg / (gx * 4);

  const int tid  = threadIdx.x;
  const int lane = tid & 63;
  const int wid  = tid >> 6;
  const int wrow = wid >> 2;
  const int wcol = wid & 3;
  const int r    = lane & 15;
  const int kg   = lane >> 4;

  const unsigned short* Ab = A + (size_t)bz * sA + (size_t)by * 256 * lda;
  const unsigned short* Bb = B + (size_t)bz * sB + (size_t)bx * 256 * ldb;

  f32x4 acc[8][4] = {};
  gemm_loop(Ab, Bb, lda, ldb, K, lds, tid, wrow, wcol, r, kg, acc);

  // epilogue: LDS transpose -> coalesced dwordx4 stores
  float* Cb = C + (size_t)bz * sC;
  const int rb = by * 256;
  const int cb = bx * 256;
  float* lf = (float*)smem;
  __syncthreads();
#pragma unroll
  for (int q = 0; q < 4; ++q) {
    if (wrow == (q & 1)) {
      const int MH = q >> 1;
#pragma unroll
      for (int i = 0; i < 4; ++i) {
#pragma unroll
        for (int n = 0; n < 4; ++n) {
          const int col  = (n >> 1) * 128 + wcol * 32 + (n & 1) * 16 + r;
          const int lrow = i * 16 + kg * 4;
          const f32x4 v = acc[MH * 4 + i][n];
#pragma unroll
          for (int j = 0; j < 4; ++j)
            lf[(lrow + j) * 260 + col] = v[j];
        }
      }
    }
    __syncthreads();
#pragma unroll
    for (int i = 0; i < 8; ++i) {
      const int chunk = i * 512 + tid;
      const int row   = chunk >> 6;
      const int cp    = (chunk & 63) * 4;
      const f32x4 v = *(const f32x4*)&lf[row * 260 + cp];
      *(f32x4*)&Cb[(size_t)(rb + q * 64 + row) * ldc + cb + cp] = v;
    }
    __syncthreads();
  }
}

// ---------------------------------------------------------------------------
// Kernel 2: row softmax, S (fp32, 16384 rows x 1024) -> attn (bf16).
// ---------------------------------------------------------------------------
__global__ __launch_bounds__(256) void softmax_rows(const float* __restrict__ S,
                                                    unsigned short* __restrict__ P) {
  __shared__ float redm[4];
  __shared__ float reds[4];
  const int t = threadIdx.x;
  const int wid = t >> 6, lane = t & 63;
  const size_t row = blockIdx.x;

  const float4 v = ((const float4*)(S + row * 1024))[t];

  float m = fmaxf(fmaxf(v.x, v.y), fmaxf(v.z, v.w));
#pragma unroll
  for (int o = 32; o >= 1; o >>= 1) m = fmaxf(m, __shfl_xor(m, o));
  if (lane == 0) redm[wid] = m;
  __syncthreads();
  m = fmaxf(fmaxf(redm[0], redm[1]), fmaxf(redm[2], redm[3]));

  const float e0 = expf(v.x - m), e1 = expf(v.y - m);
  const float e2 = expf(v.z - m), e3 = expf(v.w - m);
  float s = (e0 + e1) + (e2 + e3);
#pragma unroll
  for (int o = 32; o >= 1; o >>= 1) s += __shfl_xor(s, o);
  if (lane == 0) reds[wid] = s;
  __syncthreads();
  s = (reds[0] + reds[1]) + (reds[2] + reds[3]);

  const float inv = 1.0f / s;
  ushort4 u;
  u.x = f2bf(e0 * inv); u.y = f2bf(e1 * inv);
  u.z = f2bf(e2 * inv); u.w = f2bf(e3 * inv);
  ((ushort4*)(P + row * 1024))[t] = u;
}

// ---------------------------------------------------------------------------
extern "C" void kernel_launch(void* const* d_in, const int* in_sizes, int n_in,
                              void* d_out, int out_size, void* d_ws, size_t ws_size,
                              hipStream_t stream) {
  const float* x = (const float*)d_in[0];
  float* out = (float*)d_out;

  unsigned short* xb   = (unsigned short*)d_ws;
  unsigned short* xbT  = xb + (size_t)BATCH * C_DIM * N_DIM;
  unsigned short* attn = xb;          // overlays xb (dead after GEMM1)
  float* S = out;                     // scores staged in d_out, overwritten later

  cvt_xpose<<<dim3(N_DIM / 64, C_DIM / 64, BATCH), 256, 0, stream>>>(x, xb, xbT);

  // S[c][d] = sum_n xb[c][n] xb[d][n] : symmetric, triangle tiles only.
  gemm_sym<<<dim3(10 * BATCH), 512, 0, stream>>>(
      xb, S, N_DIM, N_DIM, C_DIM,
      (long)C_DIM * N_DIM, (long)C_DIM * C_DIM);

  softmax_rows<<<dim3(BATCH * C_DIM), 256, 0, stream>>>(S, attn);

  // out[c][n] = sum_d attn[c][d] xbT[n][d]  (M=1024, N=4096, K=1024) : gx = 16
  gemm_bt256<<<dim3((N_DIM / 256) * (C_DIM / 256) * BATCH), 512, 0, stream>>>(
      attn, xbT, out, C_DIM, C_DIM, C_DIM, N_DIM,
      (long)C_DIM * C_DIM, (long)N_DIM * C_DIM, (long)C_DIM * N_DIM,
      N_DIM / 256);
}

// Round 8
// 381.005 us; speedup vs baseline: 1.0007x; 1.0007x over previous
//
#include <hip/hip_runtime.h>
#include <hip/hip_bf16.h>

// ---------------------------------------------------------------------------
// SpatialInteraction: per-batch channel self-attention
//   S = X X^T  (c=1024, n=4096), attn = softmax_rows(S), out = attn X
// Pipeline: cvt+transpose -> SYM triangle GEMM (S) -> softmax -> bt-GEMM.
// R8 GEMM core: faithful m201 8-phase schedule. 256x256 tile, BK=64, 8 waves.
// Fixed buffer roles: even K-tiles in dbuf0, odd in dbuf1 (no flip).
// Per iteration (2 K-tiles): 8 phases, each =
//   { ds_reads for one C-quadrant; stage ONE half-tile (scheduled exactly
//     one phase after that LDS region's last read); [lgkmcnt(8) if 12 reads;
//     vmcnt(6) only at ph4/ph8]; s_barrier; lgkmcnt(0) (pinned asm - read
//     retirement); setprio(1); 16 MFMA; setprio(0); s_barrier }
// Prologue stages 7 halves + vmcnt(6); last iter drains vmcnt 4->2->0.
// T2 chunk-XOR swizzle (0 conflicts since R3), T1 XCD swizzle, LDS-transpose
// epilogue; gemm_sym writes C[i,j] and C[j,i]^T from one acc.
// ---------------------------------------------------------------------------

typedef float  f32x4  __attribute__((ext_vector_type(4)));
typedef __bf16 bf16x8 __attribute__((ext_vector_type(8)));

#define BATCH 16
#define C_DIM 1024
#define N_DIM 4096

#define VMW(N) asm volatile("s_waitcnt vmcnt(" #N ")" ::: "memory")
#define LGW(N) asm volatile("s_waitcnt lgkmcnt(" #N ")" ::: "memory")
#define SBAR do { asm volatile("" ::: "memory"); __builtin_amdgcn_s_barrier(); \
                  asm volatile("" ::: "memory"); } while (0)

__device__ __forceinline__ unsigned short f2bf(float f) {
  unsigned u = __float_as_uint(f);
  u += 0x7fffu + ((u >> 16) & 1u);        // round-to-nearest-even
  return (unsigned short)(u >> 16);
}

__device__ __forceinline__ void gld_lds16(const void* g, void* l) {
  __builtin_amdgcn_global_load_lds(
      (const __attribute__((address_space(1))) unsigned int*)g,
      (__attribute__((address_space(3))) unsigned int*)l, 16, 0, 0);
}

// ---------------------------------------------------------------------------
// Kernel 0: fp32 -> bf16 copy (xb[c][n]) + transposed copy (xbT[n][c]).
// ---------------------------------------------------------------------------
__global__ __launch_bounds__(256) void cvt_xpose(const float* __restrict__ x,
                                                 unsigned short* __restrict__ xb,
                                                 unsigned short* __restrict__ xbT) {
  __shared__ unsigned short tile[64][68];
  const int b  = blockIdx.z;
  const int c0 = blockIdx.y * 64;
  const int n0 = blockIdx.x * 64;
  const int t  = threadIdx.x;

  const float* xp = x + ((size_t)b * C_DIM + c0) * N_DIM + n0;
  const int tn = (t & 15) * 4;
  const int tc = t >> 4;

#pragma unroll
  for (int i = 0; i < 4; ++i) {
    const int c = i * 16 + tc;
    const float4 v = *(const float4*)(xp + (size_t)c * N_DIM + tn);
    ushort4 u;
    u.x = f2bf(v.x); u.y = f2bf(v.y); u.z = f2bf(v.z); u.w = f2bf(v.w);
    *(ushort4*)&tile[c][tn] = u;
    *(ushort4*)(xb + ((size_t)b * C_DIM + c0 + c) * N_DIM + n0 + tn) = u;
  }
  __syncthreads();

  const int pc = (t & 15) * 4;
  const int pn = t >> 4;
#pragma unroll
  for (int i = 0; i < 4; ++i) {
    const int n = i * 16 + pn;
    ushort4 u;
    u.x = tile[pc + 0][n];
    u.y = tile[pc + 1][n];
    u.z = tile[pc + 2][n];
    u.w = tile[pc + 3][n];
    *(ushort4*)(xbT + ((size_t)b * N_DIM + n0 + n) * C_DIM + c0 + pc) = u;
  }
}

// ---------------------------------------------------------------------------
// GEMM helpers. Each 256x64 tile region: 256 rows x 64 bf16, 8 x 16B
// chunks/row; swizzle chunk' = chunk ^ (row & 7) applied to the GLOBAL
// source on stage and to the ds_read address (LDS stays linear).
// ---------------------------------------------------------------------------

template<int H>
__device__ __forceinline__ void stage_half(const unsigned short* __restrict__ Gb,
                                           int ld, int k0,
                                           unsigned short* matbase, int tid) {
  unsigned short* lhalf = matbase + H * 128 * 64;
#pragma unroll
  for (int i = 0; i < 2; ++i) {
    const int chunk = i * 512 + tid;     // 0..1023 within half
    const int row   = chunk >> 3;        // 0..127
    const int c16   = chunk & 7;
    const int grow  = H * 128 + row;
    gld_lds16(Gb + (size_t)grow * ld + k0 + ((c16 ^ (row & 7)) * 8),
              lhalf + chunk * 8);
  }
}

template<int MH>
__device__ __forceinline__ void loadA(const unsigned short* __restrict__ As,
                                      bf16x8 (&a)[4][2], int wrow, int r, int kg) {
#pragma unroll
  for (int i = 0; i < 4; ++i) {
    const int row = MH * 128 + wrow * 64 + i * 16 + r;
#pragma unroll
    for (int kk = 0; kk < 2; ++kk) {
      const int c = kk * 4 + kg;
      a[i][kk] = *(const bf16x8*)(As + row * 64 + ((c ^ (row & 7)) * 8));
    }
  }
}

template<int NH>
__device__ __forceinline__ void loadB(const unsigned short* __restrict__ Bs,
                                      bf16x8 (&b)[2][2], int wcol, int r, int kg) {
#pragma unroll
  for (int j = 0; j < 2; ++j) {
    const int row = NH * 128 + wcol * 32 + j * 16 + r;
#pragma unroll
    for (int kk = 0; kk < 2; ++kk) {
      const int c = kk * 4 + kg;
      b[j][kk] = *(const bf16x8*)(Bs + row * 64 + ((c ^ (row & 7)) * 8));
    }
  }
}

template<int MH, int NH>
__device__ __forceinline__ void mfma16(const bf16x8 (&a)[4][2],
                                       const bf16x8 (&b)[2][2],
                                       f32x4 (&acc)[8][4]) {
  __builtin_amdgcn_s_setprio(1);
#pragma unroll
  for (int i = 0; i < 4; ++i)
#pragma unroll
    for (int j = 0; j < 2; ++j)
#pragma unroll
      for (int kk = 0; kk < 2; ++kk)
        acc[MH * 4 + i][NH * 2 + j] = __builtin_amdgcn_mfma_f32_16x16x32_bf16(
            a[i][kk], b[j][kk], acc[MH * 4 + i][NH * 2 + j], 0, 0, 0);
  __builtin_amdgcn_s_setprio(0);
}

// m201 8-phase K-loop. LDS (shorts): Ap=[0,16384) Bp=[16384,32768)
// Aq=[32768,49152) Bq=[49152,65536). Even K-tiles (P) in Ap/Bp, odd (Q) in
// Aq/Bq. K/64 must be even and >= 4.
__device__ __forceinline__ void gemm_loop8(const unsigned short* __restrict__ Ab,
                                           const unsigned short* __restrict__ Bb,
                                           int lda, int ldb, int K,
                                           unsigned short* lds, int tid,
                                           int wrow, int wcol, int r, int kg,
                                           f32x4 (&acc)[8][4]) {
  unsigned short* Ap = lds;
  unsigned short* Bp = lds + 16384;
  unsigned short* Aq = lds + 32768;
  unsigned short* Bq = lds + 49152;
  bf16x8 a[4][2], b0[2][2], b1[2][2];
  const int NI = (K / 64) / 2;             // iterations of 2 K-tiles

  // ---- prologue: P0.{A0,B0,B1,A1}, Q0.{A0,B0,B1} ; drain P0 ----
  stage_half<0>(Ab, lda, 0, Ap, tid);
  stage_half<0>(Bb, ldb, 0, Bp, tid);
  stage_half<1>(Bb, ldb, 0, Bp, tid);
  stage_half<1>(Ab, lda, 0, Ap, tid);
  stage_half<0>(Ab, lda, 64, Aq, tid);
  stage_half<0>(Bb, ldb, 64, Bq, tid);
  stage_half<1>(Bb, ldb, 64, Bq, tid);
  VMW(6); SBAR;                            // queue: [Q.A0,Q.B0,Q.B1]

  // ---- main iterations (full staging) ----
  for (int i = 0; i < NI - 1; ++i) {
    const int kQ  = i * 128 + 64;
    const int kP2 = i * 128 + 128;
    const int kQ2 = i * 128 + 192;

    // ph1: quad(0,0) of P ; stage Q.A1
    loadA<0>(Ap, a, wrow, r, kg);
    loadB<0>(Bp, b0, wcol, r, kg);
    stage_half<1>(Ab, lda, kQ, Aq, tid);
    LGW(8); SBAR; LGW(0);
    mfma16<0, 0>(a, b0, acc); SBAR;

    // ph2: quad(0,1) of P ; stage P'.A0
    loadB<1>(Bp, b1, wcol, r, kg);
    stage_half<0>(Ab, lda, kP2, Ap, tid);
    SBAR; LGW(0);
    mfma16<0, 1>(a, b1, acc); SBAR;

    // ph3: quad(1,0) of P ; stage P'.B0
    loadA<1>(Ap, a, wrow, r, kg);
    stage_half<0>(Bb, ldb, kP2, Bp, tid);
    SBAR; LGW(0);
    mfma16<1, 0>(a, b0, acc); SBAR;

    // ph4: quad(1,1) of P ; stage P'.B1 ; drain Q.{A0,B0,B1,A1}
    stage_half<1>(Bb, ldb, kP2, Bp, tid);
    VMW(6); SBAR; LGW(0);
    mfma16<1, 1>(a, b1, acc); SBAR;

    // ph5: quad(0,0) of Q ; stage P'.A1
    loadA<0>(Aq, a, wrow, r, kg);
    loadB<0>(Bq, b0, wcol, r, kg);
    stage_half<1>(Ab, lda, kP2, Ap, tid);
    LGW(8); SBAR; LGW(0);
    mfma16<0, 0>(a, b0, acc); SBAR;

    // ph6: quad(0,1) of Q ; stage Q'.A0
    loadB<1>(Bq, b1, wcol, r, kg);
    stage_half<0>(Ab, lda, kQ2, Aq, tid);
    SBAR; LGW(0);
    mfma16<0, 1>(a, b1, acc); SBAR;

    // ph7: quad(1,0) of Q ; stage Q'.B0
    loadA<1>(Aq, a, wrow, r, kg);
    stage_half<0>(Bb, ldb, kQ2, Bq, tid);
    SBAR; LGW(0);
    mfma16<1, 0>(a, b0, acc); SBAR;

    // ph8: quad(1,1) of Q ; stage Q'.B1 ; drain P'.{A0,B0,B1,A1}
    stage_half<1>(Bb, ldb, kQ2, Bq, tid);
    VMW(6); SBAR; LGW(0);
    mfma16<1, 1>(a, b1, acc); SBAR;
  }

  // ---- last iteration: only Q.A1 left to stage; drain 4 -> 2 -> 0 ----
  {
    const int kQ = (NI - 1) * 128 + 64;

    // ph1: stage Q.A1 (read at ph7)
    loadA<0>(Ap, a, wrow, r, kg);
    loadB<0>(Bp, b0, wcol, r, kg);
    stage_half<1>(Ab, lda, kQ, Aq, tid);
    LGW(8); SBAR; LGW(0);
    mfma16<0, 0>(a, b0, acc); SBAR;

    // ph2
    loadB<1>(Bp, b1, wcol, r, kg);
    SBAR; LGW(0);
    mfma16<0, 1>(a, b1, acc); SBAR;

    // ph3
    loadA<1>(Ap, a, wrow, r, kg);
    SBAR; LGW(0);
    mfma16<1, 0>(a, b0, acc); SBAR;

    // ph4: drain Q.{A0,B0}
    VMW(4); SBAR; LGW(0);
    mfma16<1, 1>(a, b1, acc); SBAR;

    // ph5: drain Q.B1
    loadA<0>(Aq, a, wrow, r, kg);
    loadB<0>(Bq, b0, wcol, r, kg);
    LGW(8); VMW(2); SBAR; LGW(0);
    mfma16<0, 0>(a, b0, acc); SBAR;

    // ph6: drain Q.A1
    loadB<1>(Bq, b1, wcol, r, kg);
    VMW(0); SBAR; LGW(0);
    mfma16<0, 1>(a, b1, acc); SBAR;

    // ph7
    loadA<1>(Aq, a, wrow, r, kg);
    SBAR; LGW(0);
    mfma16<1, 0>(a, b0, acc); SBAR;

    // ph8
    mfma16<1, 1>(a, b1, acc);
  }
}

// ---------------------------------------------------------------------------
// Kernel 1: symmetric GEMM  S = Xb Xb^T per batch, triangle tiles only.
// ---------------------------------------------------------------------------
__global__ __launch_bounds__(512, 2)
void gemm_sym(const unsigned short* __restrict__ A,
              float* __restrict__ C,
              int K, int lda, int ldc, long sA, long sC) {
  __shared__ __align__(16) unsigned char smem[131072];
  unsigned short* lds = (unsigned short*)smem;

  const int nwg  = gridDim.x;
  const int orig = blockIdx.x;
  const int wg   = (orig & 7) * (nwg >> 3) + (orig >> 3);
  const int bz   = wg / 10;
  const int p    = wg % 10;
  int ti = 0;
  while ((ti + 1) * (ti + 2) / 2 <= p) ++ti;     // ti in 0..3
  const int tj = p - ti * (ti + 1) / 2;          // tj in 0..ti

  const int tid  = threadIdx.x;
  const int lane = tid & 63;
  const int wid  = tid >> 6;
  const int wrow = wid >> 2;
  const int wcol = wid & 3;
  const int r    = lane & 15;
  const int kg   = lane >> 4;

  const unsigned short* Ab = A + (size_t)bz * sA + (size_t)ti * 256 * lda;
  const unsigned short* Bb = A + (size_t)bz * sA + (size_t)tj * 256 * lda;

  f32x4 acc[8][4] = {};
  gemm_loop8(Ab, Bb, lda, lda, K, lds, tid, wrow, wcol, r, kg, acc);

  float* Cb = C + (size_t)bz * sC;
  const int rb = ti * 256;
  const int cb = tj * 256;
  float* lf = (float*)smem;          // 64 x 260 f32 scratch
  __syncthreads();
#pragma unroll
  for (int q = 0; q < 4; ++q) {
    if (wrow == (q & 1)) {
      const int MH = q >> 1;
#pragma unroll
      for (int i = 0; i < 4; ++i) {
#pragma unroll
        for (int n = 0; n < 4; ++n) {
          const int col  = (n >> 1) * 128 + wcol * 32 + (n & 1) * 16 + r;
          const int lrow = i * 16 + kg * 4;
          const f32x4 v = acc[MH * 4 + i][n];
#pragma unroll
          for (int j = 0; j < 4; ++j)
            lf[(lrow + j) * 260 + col] = v[j];
        }
      }
    }
    __syncthreads();
#pragma unroll
    for (int i = 0; i < 8; ++i) {
      const int chunk = i * 512 + tid;     // 0..4095
      const int row   = chunk >> 6;        // 0..63
      const int cp    = (chunk & 63) * 4;  // 0..252
      const f32x4 v = *(const f32x4*)&lf[row * 260 + cp];
      *(f32x4*)&Cb[(size_t)(rb + q * 64 + row) * ldc + cb + cp] = v;
    }
    if (ti != tj) {
#pragma unroll
      for (int i = 0; i < 8; ++i) {
        const int chunk = i * 512 + tid;     // 0..4095
        const int orow  = chunk >> 4;        // 0..255 (col of lf)
        const int ocp   = (chunk & 15) * 4;  // 0..60  (row of lf)
        f32x4 v;
#pragma unroll
        for (int j = 0; j < 4; ++j)
          v[j] = lf[(ocp + j) * 260 + orow];
        *(f32x4*)&Cb[(size_t)(cb + orow) * ldc + rb + q * 64 + ocp] = v;
      }
    }
    __syncthreads();
  }
}

// ---------------------------------------------------------------------------
// Kernel 3: C[M][N] = A[M][K] * B[N][K]^T.
// 1D grid = gx * 4 * BATCH blocks, 512 threads. M fixed at 1024 (4 tiles).
// ---------------------------------------------------------------------------
__global__ __launch_bounds__(512, 2)
void gemm_bt256(const unsigned short* __restrict__ A,
                const unsigned short* __restrict__ B,
                float* __restrict__ C,
                int K, int lda, int ldb, int ldc,
                long sA, long sB, long sC, int gx) {
  __shared__ __align__(16) unsigned char smem[131072];
  unsigned short* lds = (unsigned short*)smem;

  const int nwg  = gridDim.x;
  const int orig = blockIdx.x;
  const int wg   = (orig & 7) * (nwg >> 3) + (orig >> 3);
  const int by   = wg & 3;
  const int bx   = (wg >> 2) % gx;
  const int bz   = wg / (gx * 4);

  const int tid  = threadIdx.x;
  const int lane = tid & 63;
  const int wid  = tid >> 6;
  const int wrow = wid >> 2;
  const int wcol = wid & 3;
  const int r    = lane & 15;
  const int kg   = lane >> 4;

  const unsigned short* Ab = A + (size_t)bz * sA + (size_t)by * 256 * lda;
  const unsigned short* Bb = B + (size_t)bz * sB + (size_t)bx * 256 * ldb;

  f32x4 acc[8][4] = {};
  gemm_loop8(Ab, Bb, lda, ldb, K, lds, tid, wrow, wcol, r, kg, acc);

  float* Cb = C + (size_t)bz * sC;
  const int rb = by * 256;
  const int cb = bx * 256;
  float* lf = (float*)smem;
  __syncthreads();
#pragma unroll
  for (int q = 0; q < 4; ++q) {
    if (wrow == (q & 1)) {
      const int MH = q >> 1;
#pragma unroll
      for (int i = 0; i < 4; ++i) {
#pragma unroll
        for (int n = 0; n < 4; ++n) {
          const int col  = (n >> 1) * 128 + wcol * 32 + (n & 1) * 16 + r;
          const int lrow = i * 16 + kg * 4;
          const f32x4 v = acc[MH * 4 + i][n];
#pragma unroll
          for (int j = 0; j < 4; ++j)
            lf[(lrow + j) * 260 + col] = v[j];
        }
      }
    }
    __syncthreads();
#pragma unroll
    for (int i = 0; i < 8; ++i) {
      const int chunk = i * 512 + tid;
      const int row   = chunk >> 6;
      const int cp    = (chunk & 63) * 4;
      const f32x4 v = *(const f32x4*)&lf[row * 260 + cp];
      *(f32x4*)&Cb[(size_t)(rb + q * 64 + row) * ldc + cb + cp] = v;
    }
    __syncthreads();
  }
}

// ---------------------------------------------------------------------------
// Kernel 2: row softmax, S (fp32, 16384 rows x 1024) -> attn (bf16).
// ---------------------------------------------------------------------------
__global__ __launch_bounds__(256) void softmax_rows(const float* __restrict__ S,
                                                    unsigned short* __restrict__ P) {
  __shared__ float redm[4];
  __shared__ float reds[4];
  const int t = threadIdx.x;
  const int wid = t >> 6, lane = t & 63;
  const size_t row = blockIdx.x;

  const float4 v = ((const float4*)(S + row * 1024))[t];

  float m = fmaxf(fmaxf(v.x, v.y), fmaxf(v.z, v.w));
#pragma unroll
  for (int o = 32; o >= 1; o >>= 1) m = fmaxf(m, __shfl_xor(m, o));
  if (lane == 0) redm[wid] = m;
  __syncthreads();
  m = fmaxf(fmaxf(redm[0], redm[1]), fmaxf(redm[2], redm[3]));

  const float e0 = expf(v.x - m), e1 = expf(v.y - m);
  const float e2 = expf(v.z - m), e3 = expf(v.w - m);
  float s = (e0 + e1) + (e2 + e3);
#pragma unroll
  for (int o = 32; o >= 1; o >>= 1) s += __shfl_xor(s, o);
  if (lane == 0) reds[wid] = s;
  __syncthreads();
  s = (reds[0] + reds[1]) + (reds[2] + reds[3]);

  const float inv = 1.0f / s;
  ushort4 u;
  u.x = f2bf(e0 * inv); u.y = f2bf(e1 * inv);
  u.z = f2bf(e2 * inv); u.w = f2bf(e3 * inv);
  ((ushort4*)(P + row * 1024))[t] = u;
}

// ---------------------------------------------------------------------------
extern "C" void kernel_launch(void* const* d_in, const int* in_sizes, int n_in,
                              void* d_out, int out_size, void* d_ws, size_t ws_size,
                              hipStream_t stream) {
  const float* x = (const float*)d_in[0];
  float* out = (float*)d_out;

  unsigned short* xb   = (unsigned short*)d_ws;
  unsigned short* xbT  = xb + (size_t)BATCH * C_DIM * N_DIM;
  unsigned short* attn = xb;          // overlays xb (dead after GEMM1)
  float* S = out;                     // scores staged in d_out, overwritten later

  cvt_xpose<<<dim3(N_DIM / 64, C_DIM / 64, BATCH), 256, 0, stream>>>(x, xb, xbT);

  // S[c][d] = sum_n xb[c][n] xb[d][n] : symmetric, triangle tiles only.
  gemm_sym<<<dim3(10 * BATCH), 512, 0, stream>>>(
      xb, S, N_DIM, N_DIM, C_DIM,
      (long)C_DIM * N_DIM, (long)C_DIM * C_DIM);

  softmax_rows<<<dim3(BATCH * C_DIM), 256, 0, stream>>>(S, attn);

  // out[c][n] = sum_d attn[c][d] xbT[n][d]  (M=1024, N=4096, K=1024) : gx = 16
  gemm_bt256<<<dim3((N_DIM / 256) * (C_DIM / 256) * BATCH), 512, 0, stream>>>(
      attn, xbT, out, C_DIM, C_DIM, C_DIM, N_DIM,
      (long)C_DIM * C_DIM, (long)N_DIM * C_DIM, (long)C_DIM * N_DIM,
      N_DIM / 256);
}